// Round 3
// baseline (37449.481 us; speedup 1.0000x reference)
//
#include <hip/hip_runtime.h>

// 6 chained LSTM passes (0-4 share W1/U1/b1, 5 uses W2/U2/b2). B=128,T=256,H=512.
// Persistent kernel, 256 wgs = 4 rowgroups(32 rows) x 64 colgroups(8 units).
// Round 3: no per-step L2 fences. h exchanged via IF-coherent relaxed agent
// atomics (sc0 sc1, bypass caches); per-step monotonic arrival counters
// (256 waves/rowgroup, target 256*(m+1)); x-part reads cached with ONE
// __threadfence per layer transition; ping-pong activation planes in ws.

#define TSEQ  256
#define HID   512

typedef _Float16 v8h __attribute__((ext_vector_type(8)));
typedef float    v4f __attribute__((ext_vector_type(4)));
typedef unsigned v4u __attribute__((ext_vector_type(4)));

__device__ __forceinline__ float sigm(float x)  { return 1.0f / (1.0f + __expf(-x)); }
__device__ __forceinline__ float tanhf_(float x){ return 1.0f - 2.0f / (__expf(2.0f * x) + 1.0f); }

__device__ __forceinline__ void waitge(unsigned* p, unsigned tgt) {
    while (__hip_atomic_load(p, __ATOMIC_RELAXED, __HIP_MEMORY_SCOPE_AGENT) < tgt)
        __builtin_amdgcn_s_sleep(1);
    asm volatile("" ::: "memory");   // keep h-loads below the poll
}

__device__ __forceinline__ unsigned ldc(const unsigned* p) {
    return __hip_atomic_load(p, __ATOMIC_RELAXED, __HIP_MEMORY_SCOPE_AGENT);
}

__global__ __launch_bounds__(256)
void lstm_persist(const float* __restrict__ x,
                  const float* __restrict__ W1, const float* __restrict__ U1,
                  const float* __restrict__ b1,
                  const float* __restrict__ W2, const float* __restrict__ U2,
                  const float* __restrict__ b2,
                  float* __restrict__ out,
                  _Float16* __restrict__ P0,
                  _Float16* __restrict__ P1,
                  unsigned* __restrict__ bar) {
    const int wg   = blockIdx.x;
    const int r    = (wg & 7) >> 1;                  // rowgroup 0..3
    const int cg   = ((wg >> 3) << 1) | (wg & 1);    // col-group 0..63
    const int tid  = threadIdx.x;
    const int lane = tid & 63;
    const int wv   = tid >> 6;
    const int rw   = wv >> 1;                        // row half
    const int cw   = wv & 1;                         // col half

    __shared__ _Float16 Wl[32 * 1024];               // 64 KB f16 weights, XOR-swizzled

    const int q     = lane >> 4;
    const int koffA = q << 3;
    const int arow  = (r << 5) + (rw << 4) + (lane & 15);
    const int cB    = (cw << 4) + (lane & 15);
    const int c7    = cB & 7;
    _Float16* const Bbase = Wl + (cB << 10);

    const int j4   = lane & 3;
    const int erow = (r << 5) + (rw << 4) + (q << 2) + j4;
    const int eun  = (cg << 3) + (cw << 2) + ((lane >> 2) & 3);

    unsigned* const cnt = bar + (r << 8);            // 256 counters per rowgroup

    float cst = 0.0f;
    float bI = 0.f, bF = 0.f, bG = 0.f, bO = 0.f;

    for (int m = 0; m < 6; ++m) {
        _Float16* const       Pcur  = (m & 1) ? P1 : P0;
        const _Float16* const Pprev = (m & 1) ? P0 : P1;

        if (m > 0) {
            waitge(&cnt[255], 256u * (unsigned)m);   // layer m-1 fully done
            __threadfence();                          // once/layer: inv stale L1/L2
        }

        if (m == 0 || m == 5) {
            const float* Wg = m ? W2 : W1;
            const float* Ug = m ? U2 : U1;
            const float* bg = m ? b2 : b1;
            // per-wave staging partition (waves arrive asynchronously at m==5;
            // safe: cnt[255]>=1280 implies all waves done reading old weights)
            for (int i = 0; i < 16; ++i) {
                const int idx = (wv << 10) + (i << 6) + lane;
                const int c   = idx >> 7;
                const int k8  = idx & 127;
                const int colg = ((c & 3) << 9) + (cg << 3) + (c >> 2);
                const float* src = (k8 < 64) ? (Wg + ((k8 << 3) * 2048 + colg))
                                             : (Ug + (((k8 - 64) << 3) * 2048 + colg));
                v8h v;
                #pragma unroll
                for (int j = 0; j < 8; ++j) v[j] = (_Float16)src[j * 2048];
                const int u16 = (c << 7) + (k8 ^ (c & 7));
                *(v8h*)(Wl + (u16 << 3)) = v;
            }
            bI = bg[eun]; bF = bg[512 + eun]; bG = bg[1024 + eun]; bO = bg[1536 + eun];
            __syncthreads();
        }

        for (int t = 0; t < TSEQ; ++t) {
            v4f acc = {0.f, 0.f, 0.f, 0.f};

            // ---- x-part (no recurrent dependency; issued before the wait) ----
            if (m == 0) {
                const float* xp = x + ((size_t)(arow * TSEQ + t)) * HID + koffA;
                #pragma unroll
                for (int kc = 0; kc < 16; ++kc) {
                    const float4 f0 = *(const float4*)(xp + (kc << 5));
                    const float4 f1 = *(const float4*)(xp + (kc << 5) + 4);
                    v8h a;
                    a[0] = (_Float16)f0.x; a[1] = (_Float16)f0.y;
                    a[2] = (_Float16)f0.z; a[3] = (_Float16)f0.w;
                    a[4] = (_Float16)f1.x; a[5] = (_Float16)f1.y;
                    a[6] = (_Float16)f1.z; a[7] = (_Float16)f1.w;
                    const v8h b = *(const v8h*)(Bbase + ((((kc << 2) + q) ^ c7) << 3));
                    acc = __builtin_amdgcn_mfma_f32_16x16x32_f16(a, b, acc, 0, 0, 0);
                }
            } else {
                const _Float16* xp = Pprev + ((size_t)(arow * TSEQ + t)) * HID + koffA;
                #pragma unroll
                for (int kc = 0; kc < 16; ++kc) {
                    const v8h a = *(const v8h*)(xp + (kc << 5));
                    const v8h b = *(const v8h*)(Bbase + ((((kc << 2) + q) ^ c7) << 3));
                    acc = __builtin_amdgcn_mfma_f32_16x16x32_f16(a, b, acc, 0, 0, 0);
                }
            }

            // ---- wait for h[t-1] of this layer ----
            if (t > 0) waitge(&cnt[t - 1], 256u * (unsigned)m + 256u);

            // ---- h-part via IF-coherent loads (skip at m==0,t==0: h0=0) ----
            if (!(m == 0 && t == 0)) {
                const _Float16* hb = (t == 0)
                    ? (Pprev + ((size_t)(arow * TSEQ + (TSEQ - 1))) * HID)
                    : (Pcur  + ((size_t)(arow * TSEQ + (t - 1))) * HID);
                const unsigned* hp = (const unsigned*)hb + (koffA >> 1);
                #pragma unroll
                for (int kc = 0; kc < 16; ++kc) {
                    const unsigned* p = hp + (kc << 4);
                    v4u d;
                    d[0] = ldc(p + 0); d[1] = ldc(p + 1);
                    d[2] = ldc(p + 2); d[3] = ldc(p + 3);
                    const v8h a = __builtin_bit_cast(v8h, d);
                    const v8h b = *(const v8h*)(Bbase + (((64 + (kc << 2) + q) ^ c7) << 3));
                    acc = __builtin_amdgcn_mfma_f32_16x16x32_f16(a, b, acc, 0, 0, 0);
                }
            }

            // ---- 4x4 quad transpose: lane -> (row q*4+j4, unit, gates M0..M3) ----
            float M0 = acc[0], M1 = acc[1], M2 = acc[2], M3 = acc[3];
            {
                float t0 = __shfl_xor(M1, 1, 64);
                float t1 = __shfl_xor(M0, 1, 64);
                float t2 = __shfl_xor(M3, 1, 64);
                float t3 = __shfl_xor(M2, 1, 64);
                if (j4 & 1) { M0 = t0; M2 = t2; } else { M1 = t1; M3 = t3; }
            }
            {
                float t0 = __shfl_xor(M2, 2, 64);
                float t1 = __shfl_xor(M3, 2, 64);
                float t2 = __shfl_xor(M0, 2, 64);
                float t3 = __shfl_xor(M1, 2, 64);
                if (j4 & 2) { M0 = t0; M1 = t1; } else { M2 = t2; M3 = t3; }
            }

            const float ig = sigm(M0 + bI);
            const float fg = sigm(M1 + bF);
            const float gg = tanhf_(M2 + bG);
            const float og = sigm(M3 + bO);
            cst = fg * cst + ig * gg;
            const float hval = og * tanhf_(cst);

            // ---- pack pair of units into a dword, IF-coherent store ----
            const unsigned hb16  = (unsigned)__builtin_bit_cast(unsigned short, (_Float16)hval);
            const unsigned other = (unsigned)__shfl_xor((int)hb16, 4, 64);
            if (((lane >> 2) & 1) == 0) {
                const unsigned val = hb16 | (other << 16);
                __hip_atomic_store((unsigned*)(Pcur + ((size_t)(erow * TSEQ + t)) * HID + eun),
                                   val, __ATOMIC_RELAXED, __HIP_MEMORY_SCOPE_AGENT);
            }
            if (m == 5 && t == TSEQ - 1) out[erow * HID + eun] = hval;

            // ---- publish: drain stores to coherence point, then arrive ----
            asm volatile("s_waitcnt vmcnt(0)" ::: "memory");
            if (lane == 0)
                __hip_atomic_fetch_add(&cnt[t], 1u, __ATOMIC_RELAXED, __HIP_MEMORY_SCOPE_AGENT);
        }
    }
}

extern "C" void kernel_launch(void* const* d_in, const int* in_sizes, int n_in,
                              void* d_out, int out_size, void* d_ws, size_t ws_size,
                              hipStream_t stream) {
    (void)in_sizes; (void)n_in; (void)out_size;
    const size_t SZ_P    = (size_t)128 * TSEQ * HID * sizeof(_Float16); // 33,554,432
    const size_t OFF_BAR = 2 * SZ_P;
    const size_t NEED    = OFF_BAR + 4096;   // 67,112,960 (< round-1-proven ws floor)
    if (ws_size < NEED) return;

    char* ws = (char*)d_ws;
    hipMemsetAsync(ws + OFF_BAR, 0, 4096, stream);   // arrival counters

    lstm_persist<<<256, 256, 0, stream>>>(
        (const float*)d_in[0],
        (const float*)d_in[1], (const float*)d_in[2], (const float*)d_in[3],
        (const float*)d_in[4], (const float*)d_in[5], (const float*)d_in[6],
        (float*)d_out,
        (_Float16*)ws,
        (_Float16*)(ws + SZ_P),
        (unsigned*)(ws + OFF_BAR));
}

// Round 4
// 13373.224 us; speedup vs baseline: 2.8003x; 2.8003x over previous
//
#include <hip/hip_runtime.h>

// 6 chained LSTM passes (0-4 share W1/U1/b1, 5 uses W2/U2/b2). B=128,T=256,H=512.
// Persistent kernel, 128 wgs = 4 rowgroups(32 rows) x 32 wgs(16 units = 64 z-cols).
// Full K=1024 weights f16 in 128KB LDS. h exchanged via IF-coherent uncached
// 8B loads / 4B stores in a 260-slice circular buffer [slice][row][unit] (fully
// coalesced: one wave A-frag load = 16 full 64B lines). Per-step per-wg FLAG
// DWORDS (no shared counters, no atomics RMW, no fences): producers store 1 to
// their dword after __syncthreads (vmcnt-drained); consumers ballot a 32-dword
// line. x-part reads 256-step-old slices uncached (no wait needed) and its
// MFMAs issue before the poll. c-state in registers for all 6 layers.

#define TSEQ  256
#define HID   512
#define CAP   260
#define WPR   32
#define NSTEP 1536

typedef _Float16 v8h __attribute__((ext_vector_type(8)));
typedef float    v4f __attribute__((ext_vector_type(4)));

__device__ __forceinline__ float sigm(float x)  { return 1.0f / (1.0f + __expf(-x)); }
__device__ __forceinline__ float tanhf_(float x){ return 1.0f - 2.0f / (__expf(2.0f * x) + 1.0f); }

__device__ __forceinline__ unsigned long long ld8(const unsigned long long* p) {
    return __hip_atomic_load(p, __ATOMIC_RELAXED, __HIP_MEMORY_SCOPE_AGENT);
}
__device__ __forceinline__ unsigned ld4(const unsigned* p) {
    return __hip_atomic_load(p, __ATOMIC_RELAXED, __HIP_MEMORY_SCOPE_AGENT);
}
__device__ __forceinline__ void st4(unsigned* p, unsigned v) {
    __hip_atomic_store(p, v, __ATOMIC_RELAXED, __HIP_MEMORY_SCOPE_AGENT);
}

// B-fragment from swizzled LDS: col c (0..63), 16B k-unit u (0..127)
#define BF(c, u) (*(const v8h*)(Wl + ((c) << 10) + (((u) ^ ((c) & 7)) << 3)))

__global__ __launch_bounds__(256)
void lstm_persist(const float* __restrict__ x,
                  const float* __restrict__ W1, const float* __restrict__ U1,
                  const float* __restrict__ b1,
                  const float* __restrict__ W2, const float* __restrict__ U2,
                  const float* __restrict__ b2,
                  float* __restrict__ out,
                  _Float16* __restrict__ H,     // [4][CAP][32][512] f16
                  unsigned* __restrict__ FL) {  // [4][NSTEP][32]
    const int wg   = blockIdx.x;
    const int r    = wg >> 5;
    const int wc   = wg & 31;
    const int u0   = wc << 4;            // first of this wg's 16 units
    const int tid  = threadIdx.x;
    const int lane = tid & 63;
    const int w    = tid >> 6;
    const int rw   = w >> 1;             // row tile 0/1
    const int cp   = w & 1;              // col pair 0/1
    const int q    = lane >> 4;
    const int j4   = lane & 3;
    const int a4   = (lane & 15) >> 2;

    __shared__ _Float16 Wl[64 * 1024];   // 128 KB, XOR-swizzled on 16B units

    _Float16* const Hr  = H  + (size_t)r * CAP * 32 * HID;
    unsigned* const FLr = FL + (size_t)r * NSTEP * WPR;

    const int rl     = (rw << 4) + (lane & 15);      // A row (local)
    const int grow   = (r << 5) + rl;                // A row (global)
    const int c0     = (cp << 5) + (lane & 15);      // B col, tile 0
    const int c1     = c0 + 16;                      // B col, tile 1
    const int erow_l = (rw << 4) + (q << 2) + j4;    // epilogue row (local)
    const int grow_e = (r << 5) + erow_l;            // epilogue row (global)
    const int Ut0    = u0 + (cp << 3) + a4;          // epilogue unit, tile 0
    const int Ut1    = Ut0 + 4;                      // epilogue unit, tile 1

    float cs0 = 0.0f, cs1 = 0.0f;
    float bI0, bF0, bG0, bO0, bI1, bF1, bG1, bO1;

    for (int s = 0; s < NSTEP; ++s) {
        const int m = s >> 8;
        const int t = s & 255;

        // ---- weight staging (layer 0 start, layer 5 start) ----
        if (s == 0 || s == 1280) {
            const float* Wg = s ? W2 : W1;
            const float* Ug = s ? U2 : U1;
            const float* bg = s ? b2 : b1;
            for (int it = 0; it < 32; ++it) {
                const int idx = (it << 8) + tid;     // 0..8191
                const int c   = idx >> 7;            // local z-col 0..63 (unit*4+gate)
                const int k8  = idx & 127;           // 16B k-unit
                const int gz  = ((c & 3) << 9) + u0 + (c >> 2);
                const float* src = (k8 < 64) ? (Wg + ((k8 << 3) * 2048 + gz))
                                             : (Ug + (((k8 - 64) << 3) * 2048 + gz));
                v8h v;
                #pragma unroll
                for (int j = 0; j < 8; ++j) v[j] = (_Float16)src[j * 2048];
                const int us = (c << 7) + (k8 ^ (c & 7));
                *(v8h*)(Wl + (us << 3)) = v;
            }
            bI0 = bg[Ut0]; bF0 = bg[512 + Ut0]; bG0 = bg[1024 + Ut0]; bO0 = bg[1536 + Ut0];
            bI1 = bg[Ut1]; bF1 = bg[512 + Ut1]; bG1 = bg[1024 + Ut1]; bO1 = bg[1536 + Ut1];
            __syncthreads();
        }

        v4f acc0 = {0.f, 0.f, 0.f, 0.f};
        v4f acc1 = {0.f, 0.f, 0.f, 0.f};

        // ---- x-part (k 0..511): independent of the chain, issued pre-poll ----
        if (m == 0) {
            const float* xp = x + ((size_t)grow * TSEQ + t) * HID + (q << 3);
            #pragma unroll
            for (int kc = 0; kc < 16; ++kc) {
                const float4 f0 = *(const float4*)(xp + (kc << 5));
                const float4 f1 = *(const float4*)(xp + (kc << 5) + 4);
                v8h a;
                a[0] = (_Float16)f0.x; a[1] = (_Float16)f0.y;
                a[2] = (_Float16)f0.z; a[3] = (_Float16)f0.w;
                a[4] = (_Float16)f1.x; a[5] = (_Float16)f1.y;
                a[6] = (_Float16)f1.z; a[7] = (_Float16)f1.w;
                const int u = (kc << 2) + q;
                acc0 = __builtin_amdgcn_mfma_f32_16x16x32_f16(a, BF(c0, u), acc0, 0, 0, 0);
                acc1 = __builtin_amdgcn_mfma_f32_16x16x32_f16(a, BF(c1, u), acc1, 0, 0, 0);
            }
        } else {
            const int sx = (s - 256) % CAP;
            const unsigned long long* xp =
                (const unsigned long long*)(Hr + ((size_t)sx * 32 + rl) * HID) + (q << 1);
            #pragma unroll
            for (int kc = 0; kc < 16; ++kc) {
                const unsigned long long d0 = ld8(xp + (kc << 3));
                const unsigned long long d1 = ld8(xp + (kc << 3) + 1);
                unsigned long long dd[2] = {d0, d1};
                const v8h a = __builtin_bit_cast(v8h, dd);
                const int u = (kc << 2) + q;
                acc0 = __builtin_amdgcn_mfma_f32_16x16x32_f16(a, BF(c0, u), acc0, 0, 0, 0);
                acc1 = __builtin_amdgcn_mfma_f32_16x16x32_f16(a, BF(c1, u), acc1, 0, 0, 0);
            }
        }

        // ---- wait for all 32 wgs of this rowgroup to publish step s-1 ----
        if (s > 0) {
            const unsigned* fp = FLr + (size_t)(s - 1) * WPR + (lane & 31);
            while (true) {
                const unsigned v = ld4(fp);
                if (__ballot(v != 0) == ~0ull) break;
                __builtin_amdgcn_s_sleep(1);
            }
            asm volatile("" ::: "memory");
        }

        // ---- h-part (k 512..1023), coalesced uncached 8B loads ----
        if (s > 0) {
            const int sh = (s - 1) % CAP;
            const unsigned long long* hp =
                (const unsigned long long*)(Hr + ((size_t)sh * 32 + rl) * HID) + (q << 1);
            #pragma unroll
            for (int kc = 0; kc < 16; ++kc) {
                const unsigned long long d0 = ld8(hp + (kc << 3));
                const unsigned long long d1 = ld8(hp + (kc << 3) + 1);
                unsigned long long dd[2] = {d0, d1};
                const v8h a = __builtin_bit_cast(v8h, dd);
                const int u = 64 + (kc << 2) + q;
                acc0 = __builtin_amdgcn_mfma_f32_16x16x32_f16(a, BF(c0, u), acc0, 0, 0, 0);
                acc1 = __builtin_amdgcn_mfma_f32_16x16x32_f16(a, BF(c1, u), acc1, 0, 0, 0);
            }
        }

        // ---- 4x4 quad transpose, both tiles ----
        float A0 = acc0[0], A1 = acc0[1], A2 = acc0[2], A3 = acc0[3];
        float B0 = acc1[0], B1 = acc1[1], B2 = acc1[2], B3 = acc1[3];
        {
            float t0 = __shfl_xor(A1, 1, 64), t1 = __shfl_xor(A0, 1, 64);
            float t2 = __shfl_xor(A3, 1, 64), t3 = __shfl_xor(A2, 1, 64);
            float s0 = __shfl_xor(B1, 1, 64), s1 = __shfl_xor(B0, 1, 64);
            float s2 = __shfl_xor(B3, 1, 64), s3 = __shfl_xor(B2, 1, 64);
            if (j4 & 1) { A0 = t0; A2 = t2; B0 = s0; B2 = s2; }
            else        { A1 = t1; A3 = t3; B1 = s1; B3 = s3; }
        }
        {
            float t0 = __shfl_xor(A2, 2, 64), t1 = __shfl_xor(A3, 2, 64);
            float t2 = __shfl_xor(A0, 2, 64), t3 = __shfl_xor(A1, 2, 64);
            float s0 = __shfl_xor(B2, 2, 64), s1 = __shfl_xor(B3, 2, 64);
            float s2 = __shfl_xor(B0, 2, 64), s3 = __shfl_xor(B1, 2, 64);
            if (j4 & 2) { A0 = t0; A1 = t1; B0 = s0; B1 = s1; }
            else        { A2 = t2; A3 = t3; B2 = s2; B3 = s3; }
        }
        // lane now holds gates [i,f,g,o] for (grow_e, Ut0) in A0..A3, (grow_e, Ut1) in B0..B3

        const float i0 = sigm(A0 + bI0), f0g = sigm(A1 + bF0);
        const float g0 = tanhf_(A2 + bG0), o0 = sigm(A3 + bO0);
        cs0 = f0g * cs0 + i0 * g0;
        const float hv0 = o0 * tanhf_(cs0);

        const float i1 = sigm(B0 + bI1), f1g = sigm(B1 + bF1);
        const float g1 = tanhf_(B2 + bG1), o1 = sigm(B3 + bO1);
        cs1 = f1g * cs1 + i1 * g1;
        const float hv1 = o1 * tanhf_(cs1);

        if (s < NSTEP - 1) {
            // pack adjacent units (a4, a4^1) into a dword via shfl, store uncached
            const int sw = s % CAP;
            unsigned* const hwp = (unsigned*)(Hr + ((size_t)sw * 32 + erow_l) * HID);
            const unsigned hb0 = (unsigned)__builtin_bit_cast(unsigned short, (_Float16)hv0);
            const unsigned hb1 = (unsigned)__builtin_bit_cast(unsigned short, (_Float16)hv1);
            const unsigned ob0 = (unsigned)__shfl_xor((int)hb0, 4, 64);
            const unsigned ob1 = (unsigned)__shfl_xor((int)hb1, 4, 64);
            if ((a4 & 1) == 0) {
                st4(hwp + (Ut0 >> 1), hb0 | (ob0 << 16));
                st4(hwp + (Ut1 >> 1), hb1 | (ob1 << 16));
            }
            __syncthreads();   // drains vmcnt(0) for all waves before barrier
            if (tid == 0) st4(FLr + (size_t)s * WPR + wc, 1u);
        } else {
            out[(size_t)grow_e * HID + Ut0] = hv0;
            out[(size_t)grow_e * HID + Ut1] = hv1;
        }
    }
}

extern "C" void kernel_launch(void* const* d_in, const int* in_sizes, int n_in,
                              void* d_out, int out_size, void* d_ws, size_t ws_size,
                              hipStream_t stream) {
    (void)in_sizes; (void)n_in; (void)out_size;
    const size_t SZ_H  = (size_t)4 * CAP * 32 * HID * sizeof(_Float16); // 34,078,720
    const size_t SZ_FL = (size_t)4 * NSTEP * WPR * sizeof(unsigned);   //    786,432
    const size_t NEED  = SZ_H + SZ_FL;
    if (ws_size < NEED) return;

    char* ws = (char*)d_ws;
    hipMemsetAsync(ws + SZ_H, 0, SZ_FL, stream);   // clear flags

    lstm_persist<<<128, 256, 0, stream>>>(
        (const float*)d_in[0],
        (const float*)d_in[1], (const float*)d_in[2], (const float*)d_in[3],
        (const float*)d_in[4], (const float*)d_in[5], (const float*)d_in[6],
        (float*)d_out,
        (_Float16*)ws,
        (unsigned*)(ws + SZ_H));
}